// Round 2
// baseline (146.110 us; speedup 1.0000x reference)
//
#include <hip/hip_runtime.h>
#include <hip/hip_bf16.h>

// Problem: V=50000, D=300, B=8, Q=128, W=16, L=8192
//   q_e[bq]   = sum_w emb[queries[bq,w]] / count(queries[bq,w]!=0)
//   sim[bq,l] = dot(q_e[bq], emb[labels[l]]) / max(|q_e[bq]|*|emb[labels[l]]|, 1e-8)
//   mask[bq,l]= (count!=0) && (labels[l]!=0)
// dtypes per reference: emb float32, indices int32 (harness-converted), out float32.
// Output: sim (8,128,1,8192) then mask (8,128,1,8192), flat concat = 16,777,216 floats.

#define DD   300
#define DP   320          // K padded to multiple of 32 for MFMA
#define WQ   16
#define NQ   1024         // B*Q
#define NL   8192
#define EPSV 1e-8f

typedef __bf16 bf16_t;
typedef __attribute__((ext_vector_type(8))) __bf16 bf16x8;
typedef __attribute__((ext_vector_type(4))) float f32x4;

// ---------- P1: q_e (bf16, padded), qn (fp32), has_query ----------
__global__ __launch_bounds__(320) void build_q(const float* __restrict__ emb,
                                               const int* __restrict__ queries,
                                               bf16_t* __restrict__ qe,
                                               float* __restrict__ qn,
                                               int* __restrict__ hasq) {
  const int row = blockIdx.x;      // bq
  const int d = threadIdx.x;       // 0..319
  __shared__ float red[5];

  int n = 0;
  int idx[WQ];
#pragma unroll
  for (int w = 0; w < WQ; ++w) {
    idx[w] = queries[row * WQ + w];
    n += (idx[w] != 0) ? 1 : 0;
  }

  float s = 0.f;
  if (d < DD) {
#pragma unroll
    for (int w = 0; w < WQ; ++w)
      s += emb[(size_t)idx[w] * DD + d];
  }
  const float qv = (d < DD) ? (s / (float)n) : 0.f;
  qe[(size_t)row * DP + d] = (bf16_t)qv;

  // block reduction of qv^2 over 5 waves
  float v = qv * qv;
#pragma unroll
  for (int off = 32; off > 0; off >>= 1) v += __shfl_down(v, off);
  const int wave = threadIdx.x >> 6;
  if ((threadIdx.x & 63) == 0) red[wave] = v;
  __syncthreads();
  if (threadIdx.x == 0) {
    qn[row] = sqrtf(red[0] + red[1] + red[2] + red[3] + red[4]);
    hasq[row] = (n != 0) ? 1 : 0;
  }
}

// ---------- P2: l_e (bf16, padded), ln (fp32), has_label ----------
__global__ __launch_bounds__(320) void build_l(const float* __restrict__ emb,
                                               const int* __restrict__ labels,
                                               bf16_t* __restrict__ le,
                                               float* __restrict__ lnrm,
                                               int* __restrict__ hasl) {
  const int l = blockIdx.x;
  const int d = threadIdx.x;
  __shared__ float red[5];

  const int r = labels[l];
  float v = 0.f;
  if (d < DD) v = emb[(size_t)r * DD + d];
  le[(size_t)l * DP + d] = (bf16_t)v;

  v = v * v;
#pragma unroll
  for (int off = 32; off > 0; off >>= 1) v += __shfl_down(v, off);
  const int wave = threadIdx.x >> 6;
  if ((threadIdx.x & 63) == 0) red[wave] = v;
  __syncthreads();
  if (threadIdx.x == 0) {
    lnrm[l] = sqrtf(red[0] + red[1] + red[2] + red[3] + red[4]);
    hasl[l] = (labels[l] != 0) ? 1 : 0;
  }
}

// ---------- G: 128x128-tile MFMA GEMM + fused cosine epilogue ----------
// A = qe (1024 x 320 rm), B^T = le (8192 x 320 rm). C = A . B^T.
// 4 waves/block, each a 64x64 tile (4x4 of 16x16x32 MFMA).
// Fragment layouts (guide m89/m91/m97):
//   A: A[m = lane&15][k = quad*8 + j];  B fed from B^T rows with same indexing
//   C: row m = quad*4 + reg, col n = lane&15
__global__ __launch_bounds__(256) void gemm_cos(const bf16_t* __restrict__ qe,
                                                const bf16_t* __restrict__ le,
                                                const float* __restrict__ qn,
                                                const float* __restrict__ lnrm,
                                                float* __restrict__ out) {
  const int n0 = blockIdx.x * 128;
  const int m0 = blockIdx.y * 128;
  const int tid = threadIdx.x;
  const int wave = tid >> 6;
  const int lane = tid & 63;
  const int wm = (wave & 1) * 64;
  const int wn = (wave >> 1) * 64;
  const int l16 = lane & 15;
  const int quad = lane >> 4;

  f32x4 acc[4][4] = {};

  for (int kb = 0; kb < 10; ++kb) {
    const int ko = kb * 32 + quad * 8;
    bf16x8 a[4], b[4];
#pragma unroll
    for (int i = 0; i < 4; ++i) {
      a[i] = *(const bf16x8*)(qe + (size_t)(m0 + wm + i * 16 + l16) * DP + ko);
      b[i] = *(const bf16x8*)(le + (size_t)(n0 + wn + i * 16 + l16) * DP + ko);
    }
#pragma unroll
    for (int i = 0; i < 4; ++i)
#pragma unroll
      for (int j = 0; j < 4; ++j)
        acc[i][j] = __builtin_amdgcn_mfma_f32_16x16x32_bf16(a[i], b[j], acc[i][j], 0, 0, 0);
  }

  // epilogue: sim = acc / max(qn*ln, eps)
  float lv[4];
#pragma unroll
  for (int j = 0; j < 4; ++j) lv[j] = lnrm[n0 + wn + j * 16 + l16];

#pragma unroll
  for (int i = 0; i < 4; ++i) {
#pragma unroll
    for (int r = 0; r < 4; ++r) {
      const int m = m0 + wm + i * 16 + quad * 4 + r;
      const float qv = qn[m];
      const size_t base = (size_t)m * NL;
#pragma unroll
      for (int j = 0; j < 4; ++j) {
        const int n = n0 + wn + j * 16 + l16;
        const float den = fmaxf(qv * lv[j], EPSV);
        out[base + n] = acc[i][j][r] / den;
      }
    }
  }
}

// ---------- M: mask = hasq[m] && hasl[n], fully coalesced float4 stores ----------
__global__ __launch_bounds__(256) void mask_k(const int* __restrict__ hasq,
                                              const int* __restrict__ hasl,
                                              float* __restrict__ outm) {
  const int t = blockIdx.x * blockDim.x + threadIdx.x;  // one float4 each
  const int m = t >> 11;           // / (NL/4 = 2048)
  const int n4 = (t & 2047) << 2;
  const int hq = hasq[m];
  f32x4 v;
#pragma unroll
  for (int k = 0; k < 4; ++k)
    v[k] = (hq && hasl[n4 + k]) ? 1.f : 0.f;
  *(f32x4*)(outm + (size_t)t * 4) = v;
}

extern "C" void kernel_launch(void* const* d_in, const int* in_sizes, int n_in,
                              void* d_out, int out_size, void* d_ws, size_t ws_size,
                              hipStream_t stream) {
  const float* emb = (const float*)d_in[0];     // 50000 x 300 f32
  const int* queries = (const int*)d_in[1];     // 8*128*16 int32
  const int* labels = (const int*)d_in[2];      // 8192 int32

  char* ws = (char*)d_ws;
  bf16_t* qe   = (bf16_t*)(ws);                 // 1024*320*2  = 655360 B
  bf16_t* le   = (bf16_t*)(ws + 655360);        // 8192*320*2  = 5242880 B
  float*  qn   = (float*) (ws + 5898240);       // 1024*4
  float*  lnrm = (float*) (ws + 5902336);       // 8192*4
  int*    hasq = (int*)   (ws + 5935104);       // 1024*4
  int*    hasl = (int*)   (ws + 5939200);       // 8192*4  (end ~5.95 MB)

  float* out = (float*)d_out;

  build_q<<<NQ, 320, 0, stream>>>(emb, queries, qe, qn, hasq);
  build_l<<<NL, 320, 0, stream>>>(emb, labels, le, lnrm, hasl);
  gemm_cos<<<dim3(NL / 128, NQ / 128), 256, 0, stream>>>(qe, le, qn, lnrm, out);
  mask_k<<<(NQ * NL / 4) / 256, 256, 0, stream>>>(hasq, hasl, out + (size_t)NQ * NL);
}

// Round 3
// 139.676 us; speedup vs baseline: 1.0461x; 1.0461x over previous
//
#include <hip/hip_runtime.h>
#include <hip/hip_bf16.h>

// Problem: V=50000, D=300, B=8, Q=128, W=16, L=8192
//   q_e[bq]   = sum_w emb[queries[bq,w]] / count(queries[bq,w]!=0)
//   sim[bq,l] = dot(q_e[bq], emb[labels[l]]) / max(|q_e[bq]|*|emb[labels[l]]|, 1e-8)
//   mask[bq,l]= (count!=0) && (labels[l]!=0)
// dtypes: emb float32, indices int32 (harness-converted), out float32.
// Output: sim (8,128,1,8192) then mask (8,128,1,8192) = 16,777,216 floats.

#define DD   300
#define DP   320          // K padded to multiple of 32 for MFMA
#define WQ   16
#define NQ   1024         // B*Q
#define NL   8192
#define EPSV 1e-8f

typedef __bf16 bf16_t;
typedef __attribute__((ext_vector_type(8))) __bf16 bf16x8;
typedef __attribute__((ext_vector_type(4))) float f32x4;

// ---------- P: fused q_e + l_e build (bf16 padded rows, fp32 norms, flags) ----------
// blocks [0, NQ)        -> q path (gather 16 rows, avg, norm)
// blocks [NQ, NQ+NL)    -> l path (gather 1 row, norm)
__global__ __launch_bounds__(320) void build_ql(const float* __restrict__ emb,
                                                const int* __restrict__ queries,
                                                const int* __restrict__ labels,
                                                bf16_t* __restrict__ qe,
                                                bf16_t* __restrict__ le,
                                                float* __restrict__ qn,
                                                float* __restrict__ lnrm,
                                                int* __restrict__ hasq,
                                                int* __restrict__ hasl) {
  const int blk = blockIdx.x;
  const int d = threadIdx.x;       // 0..319
  __shared__ float red[5];
  float v;                          // value whose square gets reduced

  if (blk < NQ) {
    // ----- query path -----
    int n = 0;
    int idx[WQ];
#pragma unroll
    for (int w = 0; w < WQ; ++w) {
      idx[w] = queries[blk * WQ + w];
      n += (idx[w] != 0) ? 1 : 0;
    }
    float s = 0.f;
    if (d < DD) {
#pragma unroll
      for (int w = 0; w < WQ; ++w)
        s += emb[(size_t)idx[w] * DD + d];
    }
    const float qv = (d < DD) ? (s / (float)n) : 0.f;
    qe[(size_t)blk * DP + d] = (bf16_t)qv;
    v = qv;
    if (d == 0) hasq[blk] = (n != 0) ? 1 : 0;
  } else {
    // ----- label path -----
    const int l = blk - NQ;
    const int r = labels[l];
    float lv = 0.f;
    if (d < DD) lv = emb[(size_t)r * DD + d];
    le[(size_t)l * DP + d] = (bf16_t)lv;
    v = lv;
    if (d == 0) hasl[l] = (r != 0) ? 1 : 0;
  }

  // block reduction of v^2 over 5 waves
  v = v * v;
#pragma unroll
  for (int off = 32; off > 0; off >>= 1) v += __shfl_down(v, off);
  if ((threadIdx.x & 63) == 0) red[threadIdx.x >> 6] = v;
  __syncthreads();
  if (threadIdx.x == 0) {
    const float nrm = sqrtf(red[0] + red[1] + red[2] + red[3] + red[4]);
    if (blk < NQ) qn[blk] = nrm; else lnrm[blk - NQ] = nrm;
  }
}

// ---------- G: 64(m) x 128(n) block tile, 4 waves each 32x64; fused cosine + mask ----------
// A = qe (1024 x 320 rm), B^T = le (8192 x 320 rm). C = A . B^T.
// Fragment layouts (guide m89/m91/m97, validated in R2):
//   A: A[m = lane&15][k = quad*8 + j];  B fed from B^T rows with same indexing
//   C: row m = quad*4 + reg, col n = lane&15
__global__ __launch_bounds__(256) void gemm_cos(const bf16_t* __restrict__ qe,
                                                const bf16_t* __restrict__ le,
                                                const float* __restrict__ qn,
                                                const float* __restrict__ lnrm,
                                                const int* __restrict__ hasq,
                                                const int* __restrict__ hasl,
                                                float* __restrict__ out) {
  const int n0 = blockIdx.x * 128;
  const int m0 = blockIdx.y * 64;
  const int wave = threadIdx.x >> 6;
  const int lane = threadIdx.x & 63;
  const int wm = (wave & 1) * 32;   // waves 2x2 over the 64x128 tile
  const int wn = (wave >> 1) * 64;
  const int l16 = lane & 15;
  const int quad = lane >> 4;

  f32x4 acc[2][4] = {};

  for (int kb = 0; kb < 10; ++kb) {
    const int ko = kb * 32 + quad * 8;
    bf16x8 a[2], b[4];
#pragma unroll
    for (int i = 0; i < 2; ++i)
      a[i] = *(const bf16x8*)(qe + (size_t)(m0 + wm + i * 16 + l16) * DP + ko);
#pragma unroll
    for (int j = 0; j < 4; ++j)
      b[j] = *(const bf16x8*)(le + (size_t)(n0 + wn + j * 16 + l16) * DP + ko);
#pragma unroll
    for (int i = 0; i < 2; ++i)
#pragma unroll
      for (int j = 0; j < 4; ++j)
        acc[i][j] = __builtin_amdgcn_mfma_f32_16x16x32_bf16(a[i], b[j], acc[i][j], 0, 0, 0);
  }

  // epilogue: sim = acc / max(qn*ln, eps); mask = hasq && hasl
  float lv[4];
  int hl[4];
#pragma unroll
  for (int j = 0; j < 4; ++j) {
    const int n = n0 + wn + j * 16 + l16;
    lv[j] = lnrm[n];
    hl[j] = hasl[n];
  }

  float* const outm = out + (size_t)NQ * NL;
#pragma unroll
  for (int i = 0; i < 2; ++i) {
#pragma unroll
    for (int r = 0; r < 4; ++r) {
      const int m = m0 + wm + i * 16 + quad * 4 + r;
      const float qv = qn[m];
      const int hq = hasq[m];
      const size_t base = (size_t)m * NL;
#pragma unroll
      for (int j = 0; j < 4; ++j) {
        const int n = n0 + wn + j * 16 + l16;
        const float den = fmaxf(qv * lv[j], EPSV);
        out[base + n] = acc[i][j][r] * __builtin_amdgcn_rcpf(den);
        outm[base + n] = (hq && hl[j]) ? 1.f : 0.f;
      }
    }
  }
}

extern "C" void kernel_launch(void* const* d_in, const int* in_sizes, int n_in,
                              void* d_out, int out_size, void* d_ws, size_t ws_size,
                              hipStream_t stream) {
  const float* emb = (const float*)d_in[0];     // 50000 x 300 f32
  const int* queries = (const int*)d_in[1];     // 8*128*16 int32
  const int* labels = (const int*)d_in[2];      // 8192 int32

  char* ws = (char*)d_ws;
  bf16_t* qe   = (bf16_t*)(ws);                 // 1024*320*2  = 655360 B
  bf16_t* le   = (bf16_t*)(ws + 655360);        // 8192*320*2  = 5242880 B
  float*  qn   = (float*) (ws + 5898240);       // 1024*4
  float*  lnrm = (float*) (ws + 5902336);       // 8192*4
  int*    hasq = (int*)   (ws + 5935104);       // 1024*4
  int*    hasl = (int*)   (ws + 5939200);       // 8192*4  (end ~5.95 MB)

  float* out = (float*)d_out;

  build_ql<<<NQ + NL, 320, 0, stream>>>(emb, queries, labels, qe, le, qn, lnrm, hasq, hasl);
  gemm_cos<<<dim3(NL / 128, NQ / 64), 256, 0, stream>>>(qe, le, qn, lnrm, hasq, hasl, out);
}